// Round 7
// baseline (309.452 us; speedup 1.0000x reference)
//
#include <hip/hip_runtime.h>
#include <stdint.h>

#define TOKENS 8192
#define INF    4096
#define OUTF   4096
#define BM     256
#define BN     128
#define NTIL   64   // K-tiles of BK=64

typedef __bf16 bf16x8 __attribute__((ext_vector_type(8)));
typedef float  f32x4  __attribute__((ext_vector_type(4)));
typedef unsigned short ushort_t;

// ---------- fp32 -> bf16 (RNE) ----------
__device__ __forceinline__ unsigned short f2bf(float f) {
  union { float f; unsigned int u; } v;
  v.f = f;
  unsigned int r = v.u + 0x7fffu + ((v.u >> 16) & 1u);
  return (unsigned short)(r >> 16);
}

__global__ void l2b_conv_x(const float* __restrict__ x,
                           unsigned short* __restrict__ xb, int n4) {
  int idx = blockIdx.x * blockDim.x + threadIdx.x;
  int stride = gridDim.x * blockDim.x;
  for (int i = idx; i < n4; i += stride) {
    float4 v = reinterpret_cast<const float4*>(x)[i];
    ushort4 o;
    o.x = f2bf(v.x); o.y = f2bf(v.y); o.z = f2bf(v.z); o.w = f2bf(v.w);
    reinterpret_cast<ushort4*>(xb)[i] = o;
  }
}

__global__ void l2b_conv_w(const int* __restrict__ w,
                           unsigned short* __restrict__ wb, int n4) {
  int idx = blockIdx.x * blockDim.x + threadIdx.x;
  int stride = gridDim.x * blockDim.x;
  for (int i = idx; i < n4; i += stride) {
    int4 v = reinterpret_cast<const int4*>(w)[i];
    ushort4 o;  // {-2,-1,0,1}: exact in bf16
    o.x = f2bf((float)v.x); o.y = f2bf((float)v.y);
    o.z = f2bf((float)v.z); o.w = f2bf((float)v.w);
    reinterpret_cast<ushort4*>(wb)[i] = o;
  }
}

// ---------- async global->LDS, 16B/lane (dest = wave base + lane*16) ---------
__device__ __forceinline__ void gload_lds16(const ushort_t* g, ushort_t* l) {
  auto gp = reinterpret_cast<__attribute__((address_space(1))) unsigned int*>(
      reinterpret_cast<uintptr_t>(g));
  auto lp = reinterpret_cast<__attribute__((address_space(3))) unsigned int*>(
      reinterpret_cast<uintptr_t>(l));
  __builtin_amdgcn_global_load_lds(gp, lp, 16, 0, 0);
}

// ---------- st_16x32-style swizzle on byte offsets (R3-proven, 0 conflicts) --
__device__ __forceinline__ int swz(int b) { return b ^ (((b >> 9) & 1) << 5); }

__device__ __forceinline__ bf16x8 ldsRd(const ushort_t* slot, int row, int colb) {
  int off = (row << 7) | colb;    // rows x 64 bf16 (128 B); row<=255 ok
  off ^= ((off >> 9) & 1) << 5;
  return *reinterpret_cast<const bf16x8*>(
      reinterpret_cast<const char*>(slot) + off);
}

__device__ __forceinline__ f32x4 mfma(bf16x8 a, bf16x8 b, f32x4 c) {
  return __builtin_amdgcn_mfma_f32_16x16x32_bf16(a, b, c, 0, 0, 0);
}

// rule #18: sched_barrier(0) after EVERY inline-asm wait (R6 lesson: the MFMA
// cluster otherwise hoists past the wait and the phase discipline dissolves)
#define LGKM8() do { asm volatile("s_waitcnt lgkmcnt(8)" ::: "memory"); \
                     __builtin_amdgcn_sched_barrier(0); } while (0)
#define LGKM0() do { asm volatile("s_waitcnt lgkmcnt(0)" ::: "memory"); \
                     __builtin_amdgcn_sched_barrier(0); } while (0)

// ================= one K-tile: 2 MFMA phases, 1 barrier, counted waits =======
// entering: a0/b0 (ph1 frags of tile t, k-half 0) already in registers,
//           read from slot(t) during tile t-1's phase-2 window.
// A: issue 6 global_load_lds -> slot(t+2)   [overlaps everything below]
// B: ds_read ph2 frags (k-half 1) from slot(t)            [8 reads]
// C: lgkm(8) [F(t-1) done, B outstanding] -> 16 MFMA ph1
// D: vmcnt(6): oldest 6 = tile(t+1)'s stages -> slot(t+1) fully landed
// E: barrier (all waves' t+1 data visible; skew bounded to <1 tile)
// F: pre-read ph1 frags of tile t+1 from slot(t+1)        [8 reads]
// G: lgkm(8) [B done, F outstanding] -> 16 MFMA ph2
// Slot-reuse safety: stage A(t)->slot(t+2)=slot(t-1); its last readers were
// B(t-1) (drained at G(t-1) lgkm) and F(t-2) (drained at C(t-1) lgkm), both
// >=1 barrier + >=600cy HBM latency before the write lands.
template <int VMB, bool STG, bool PRER>
__device__ __forceinline__ void ktile(
    const ushort_t* __restrict__ A, const ushort_t* __restrict__ B,
    int rowBlk, int colBlk, int t,
    const ushort_t* rA, const ushort_t* rB,   // slot(t)
    const ushort_t* nA, const ushort_t* nB,   // slot(t+1)
    ushort_t* sA, ushort_t* sB,               // slot(t+2)
    bf16x8 (&a0)[4], bf16x8 (&b0)[4], f32x4 (&acc)[4][4],
    int ar, int brw, int fk, int wid, const int (&geA)[4], const int (&geB)[2]) {
  // ---- A: stage tile t+2 ----
  if (STG) {
    const ushort_t* gA = A + (size_t)rowBlk * INF + (t + 2) * 64;
    const ushort_t* gB = B + (size_t)colBlk * INF + (t + 2) * 64;
#pragma unroll
    for (int r = 0; r < 4; ++r)
      gload_lds16(gA + geA[r], sA + r * 4096 + wid * 512);
#pragma unroll
    for (int r = 0; r < 2; ++r)
      gload_lds16(gB + geB[r], sB + r * 4096 + wid * 512);
  }
  // ---- B: ph2 frag reads (k-half 1) from slot t ----
  bf16x8 a1[4], b1[4];
#pragma unroll
  for (int m = 0; m < 4; ++m) a1[m] = ldsRd(rA, ar + m * 16, 64 + fk * 16);
#pragma unroll
  for (int n = 0; n < 4; ++n) b1[n] = ldsRd(rB, brw + n * 16, 64 + fk * 16);
  // ---- C: MFMA phase 1 ----
  LGKM8();
  __builtin_amdgcn_s_setprio(1);
#pragma unroll
  for (int m = 0; m < 4; ++m)
#pragma unroll
    for (int n = 0; n < 4; ++n)
      acc[m][n] = mfma(a0[m], b0[n], acc[m][n]);
  __builtin_amdgcn_s_setprio(0);
  // ---- D/E: counted vmcnt + barrier ----
  if (VMB == 6) asm volatile("s_waitcnt vmcnt(6)" ::: "memory");
  if (VMB == 0) asm volatile("s_waitcnt vmcnt(0)" ::: "memory");
  __builtin_amdgcn_s_barrier();
  // ---- F: pre-read next tile's ph1 frags from slot t+1 ----
  if (PRER) {
#pragma unroll
    for (int m = 0; m < 4; ++m) a0[m] = ldsRd(nA, ar + m * 16, fk * 16);
#pragma unroll
    for (int n = 0; n < 4; ++n) b0[n] = ldsRd(nB, brw + n * 16, fk * 16);
  }
  // ---- G: MFMA phase 2 ----
  if (PRER) { LGKM8(); } else { LGKM0(); }
  __builtin_amdgcn_s_setprio(1);
#pragma unroll
  for (int m = 0; m < 4; ++m)
#pragma unroll
    for (int n = 0; n < 4; ++n)
      acc[m][n] = mfma(a1[m], b1[n], acc[m][n]);
  __builtin_amdgcn_s_setprio(0);
}

// ============ 256x128 GEMM, BK=64, 3-slot LDS (144 KiB), 1 barrier/tile ======
__global__ __launch_bounds__(512, 2) void l2b_gemmP(
    const ushort_t* __restrict__ A, const ushort_t* __restrict__ B,
    const float* __restrict__ scale, const float* __restrict__ bias,
    float* __restrict__ C) {
  extern __shared__ ushort_t smem[];  // 3 slots x (A 16384 + B 8192 elems)
  ushort_t* slA[3] = { smem, smem + 24576, smem + 49152 };
  ushort_t* slB[3] = { smem + 16384, smem + 40960, smem + 65536 };

  const int tid  = threadIdx.x;
  const int lane = tid & 63;
  const int wid  = tid >> 6;              // 0..7
  const int wm = wid >> 1, wn = wid & 1;  // 4x2 wave grid, wave tile 64x64
  const int fr = lane & 15, fk = lane >> 4;
  const int ar  = wm * 64 + fr;           // A row in 256-row tile
  const int brw = wn * 64 + fr;           // B row in 128-row tile

  // XCD-aware swizzle (nwg=1024, divisible by 8)
  const int bid = (int)blockIdx.x;
  const int idx = (bid & 7) * 128 + (bid >> 3);
  const int bm = idx >> 5, bn = idx & 31;     // 32 x 32 tiles
  const int rowBlk = bm * BM, colBlk = bn * BN;

  // inverse-swizzled per-thread global element offsets per staging round
  int geA[4], geB[2];
#pragma unroll
  for (int r = 0; r < 4; ++r) {
    const int p = swz(r * 8192 + tid * 16);
    geA[r] = (p >> 7) * INF + ((p & 127) >> 1);
  }
#pragma unroll
  for (int r = 0; r < 2; ++r) {
    const int p = swz(r * 8192 + tid * 16);
    geB[r] = (p >> 7) * INF + ((p & 127) >> 1);
  }

  // ---- prologue: stage slot0 (t=0), slot1 (t=1); vmcnt(6) -> slot0 landed ---
  {
    const ushort_t* gA = A + (size_t)rowBlk * INF;
    const ushort_t* gB = B + (size_t)colBlk * INF;
#pragma unroll
    for (int r = 0; r < 4; ++r) gload_lds16(gA + geA[r], slA[0] + r * 4096 + wid * 512);
#pragma unroll
    for (int r = 0; r < 2; ++r) gload_lds16(gB + geB[r], slB[0] + r * 4096 + wid * 512);
#pragma unroll
    for (int r = 0; r < 4; ++r) gload_lds16(gA + 64 + geA[r], slA[1] + r * 4096 + wid * 512);
#pragma unroll
    for (int r = 0; r < 2; ++r) gload_lds16(gB + 64 + geB[r], slB[1] + r * 4096 + wid * 512);
  }
  asm volatile("s_waitcnt vmcnt(6)" ::: "memory");
  __builtin_amdgcn_s_barrier();

  // pre-read tile 0 phase-1 fragments
  bf16x8 a0[4], b0[4];
#pragma unroll
  for (int m = 0; m < 4; ++m) a0[m] = ldsRd(slA[0], ar + m * 16, fk * 16);
#pragma unroll
  for (int n = 0; n < 4; ++n) b0[n] = ldsRd(slB[0], brw + n * 16, fk * 16);

  f32x4 acc[4][4] = {};

  const ushort_t *rA = slA[0], *rB = slB[0], *nA = slA[1], *nB = slB[1];
  ushort_t *sA = slA[2], *sB = slB[2];

#pragma unroll 1
  for (int t = 0; t < NTIL - 2; ++t) {      // tiles 0..61
    ktile<6, true, true>(A, B, rowBlk, colBlk, t,
        rA, rB, nA, nB, sA, sB, a0, b0, acc, ar, brw, fk, wid, geA, geB);
    const ushort_t* tA = rA; const ushort_t* tB = rB;
    rA = nA; rB = nB; nA = sA; nB = sB;
    sA = const_cast<ushort_t*>(tA); sB = const_cast<ushort_t*>(tB);
  }
  // tile 62: no stage; drain vmcnt (outstanding = tile 63's 6 loads)
  ktile<0, false, true>(A, B, rowBlk, colBlk, NTIL - 2,
      rA, rB, nA, nB, sA, sB, a0, b0, acc, ar, brw, fk, wid, geA, geB);
  {
    const ushort_t* tA = rA; const ushort_t* tB = rB;
    rA = nA; rB = nB; nA = sA; nB = sB;
    sA = const_cast<ushort_t*>(tA); sB = const_cast<ushort_t*>(tB);
  }
  // tile 63: compute only
  ktile<-1, false, false>(A, B, rowBlk, colBlk, NTIL - 1,
      rA, rB, nA, nB, sA, sB, a0, b0, acc, ar, brw, fk, wid, geA, geB);

  // ---- epilogue: y = acc*scale + bias; C/D: col=lane&15, row=(lane>>4)*4+j --
  const float s = scale[0];
#pragma unroll
  for (int n = 0; n < 4; ++n) {
    const int col = colBlk + wn * 64 + n * 16 + fr;
    const float bv = bias[col];
#pragma unroll
    for (int m = 0; m < 4; ++m) {
      const int row = rowBlk + wm * 64 + m * 16 + fk * 4;
#pragma unroll
      for (int j = 0; j < 4; ++j)
        C[(size_t)(row + j) * OUTF + col] = acc[m][n][j] * s + bv;
    }
  }
}

// ---------------- fallback: R1 128x128 m97-structure GEMM -------------------
__global__ __launch_bounds__(256) void l2b_gemm(
    const ushort_t* __restrict__ A, const ushort_t* __restrict__ B,
    const float* __restrict__ scale, const float* __restrict__ bias,
    float* __restrict__ C) {
  constexpr int K = INF;
  constexpr int N = OUTF;
  __shared__ __align__(16) ushort_t ldsA[128 * 32];
  __shared__ __align__(16) ushort_t ldsB[128 * 32];
  const int tid = threadIdx.x;
  const int lane = tid & 63;
  const int wid = tid >> 6;
  const int wm = wid >> 1, wn = wid & 1;
  const int bm = blockIdx.x >> 5, bn = blockIdx.x & 31;
  const int row0 = bm * 128, col0 = bn * 128;
  const int lr = lane >> 4, lc = lane & 15;
  f32x4 acc[4][4] = {};
  for (int k0 = 0; k0 < K; k0 += 32) {
#pragma unroll
    for (int i = 0; i < 2; ++i) {
      const int idx = i * 256 + tid;
      const int r = idx >> 2;
      const int c = (idx & 3) * 8;
      ushort_t* lbaseA = ldsA + i * 2048 + wid * 512;
      ushort_t* lbaseB = ldsB + i * 2048 + wid * 512;
      gload_lds16(A + (size_t)(row0 + r) * K + (k0 + c), lbaseA);
      gload_lds16(B + (size_t)(col0 + r) * K + (k0 + c), lbaseB);
    }
    __syncthreads();
    bf16x8 af[4], bfr[4];
#pragma unroll
    for (int m = 0; m < 4; ++m)
      af[m] = *reinterpret_cast<const bf16x8*>(
          &ldsA[(wm * 64 + m * 16 + lc) * 32 + lr * 8]);
#pragma unroll
    for (int n = 0; n < 4; ++n)
      bfr[n] = *reinterpret_cast<const bf16x8*>(
          &ldsB[(wn * 64 + n * 16 + lc) * 32 + lr * 8]);
#pragma unroll
    for (int m = 0; m < 4; ++m)
#pragma unroll
      for (int n = 0; n < 4; ++n)
        acc[m][n] = mfma(af[m], bfr[n], acc[m][n]);
    __syncthreads();
  }
  const float s = scale[0];
#pragma unroll
  for (int n = 0; n < 4; ++n) {
    const int col = col0 + wn * 64 + n * 16 + lc;
    const float bv = bias[col];
#pragma unroll
    for (int m = 0; m < 4; ++m) {
      const int row = row0 + wm * 64 + m * 16 + lr * 4;
#pragma unroll
      for (int i = 0; i < 4; ++i)
        C[(size_t)(row + i) * N + col] = acc[m][n][i] * s + bv;
    }
  }
}

__global__ void l2b_naive(const float* __restrict__ x, const int* __restrict__ w,
                          const float* __restrict__ scale,
                          const float* __restrict__ bias,
                          float* __restrict__ out) {
  const int o = blockIdx.x * blockDim.x + threadIdx.x;
  if (o >= TOKENS * OUTF) return;
  const int t = o / OUTF;
  const int n = o - t * OUTF;
  const float* xr = x + (size_t)t * INF;
  const int* wr = w + (size_t)n * INF;
  float acc = 0.f;
  for (int k = 0; k < INF; ++k) acc += xr[k] * (float)wr[k];
  out[o] = acc * scale[0] + bias[n];
}

extern "C" void kernel_launch(void* const* d_in, const int* in_sizes, int n_in,
                              void* d_out, int out_size, void* d_ws, size_t ws_size,
                              hipStream_t stream) {
  const float* x     = (const float*)d_in[0];
  const int*   wq    = (const int*)d_in[1];
  const float* scale = (const float*)d_in[2];
  const float* bias  = (const float*)d_in[3];
  float* out = (float*)d_out;

  const size_t xbytes = (size_t)TOKENS * INF * 2;
  const size_t wbytes = (size_t)OUTF * INF * 2;

  if (ws_size >= xbytes + wbytes) {
    unsigned short* xb = (unsigned short*)d_ws;
    unsigned short* wb = (unsigned short*)((char*)d_ws + xbytes);
    l2b_conv_x<<<2048, 256, 0, stream>>>(x, xb, TOKENS * INF / 4);
    l2b_conv_w<<<2048, 256, 0, stream>>>(wq, wb, OUTF * INF / 4);

    hipError_t e = hipFuncSetAttribute(
        reinterpret_cast<const void*>(l2b_gemmP),
        hipFuncAttributeMaxDynamicSharedMemorySize, 147456);
    if (e == hipSuccess) {
      l2b_gemmP<<<dim3((TOKENS / BM) * (OUTF / BN)), 512, 147456, stream>>>(
          xb, wb, scale, bias, out);
    } else {
      l2b_gemm<<<dim3((TOKENS / 128) * (OUTF / 128)), 256, 0, stream>>>(
          xb, wb, scale, bias, out);
    }
  } else {
    l2b_naive<<<(TOKENS * OUTF + 255) / 256, 256, 0, stream>>>(
        x, wq, scale, bias, out);
  }
}